// Round 2
// baseline (259.799 us; speedup 1.0000x reference)
//
#include <hip/hip_runtime.h>
#include <hip/hip_bf16.h>
#include <stdint.h>

// CapsuleLayer dynamic routing, MI355X (gfx950).
// B=64, I=2048, P=16, J=32, D=16, ROUTINGS=3.
// Round 2: k_uhat via MFMA (bf16, K zero-padded to 32); routing passes with
// no-max softmax + rcp + higher occupancy; pass0 specialized to uniform c.

namespace {
constexpr int B_ = 64;
constexpr int I_ = 2048;
constexpr int P_ = 16;
constexpr int J_ = 32;
constexpr int D_ = 16;
constexpr int CI_ = 64;     // i-range per routing block
constexpr int ROWS_ = J_ * D_;  // 512 output rows per i

using short8 = __attribute__((ext_vector_type(8))) short;
using f32x4  = __attribute__((ext_vector_type(4))) float;

__device__ __forceinline__ float bflo(uint32_t v) {
  union { uint32_t u; float f; } z; z.u = v << 16; return z.f;
}
__device__ __forceinline__ float bfhi(uint32_t v) {
  union { uint32_t u; float f; } z; z.u = v & 0xffff0000u; return z.f;
}
__device__ __forceinline__ uint16_t f2bf(float f) {  // RNE float->bf16
  uint32_t u = __float_as_uint(f);
  u += 0x7fffu + ((u >> 16) & 1u);
  return (uint16_t)(u >> 16);
}

// ---------------------------------------------------------------------------
// K0: u_hat[b,i,row] = sum_p x[b,i,p] * W[i,row,p], stored bf16 as [b][i][row].
// One block per i; 4 waves. Per block: A = x_i [64x16], B = W_i^T [16x512],
// MFMA 16x16x32 bf16 with k=16..31 zero-padded. Wave w owns N-tiles 8w..8w+7
// (rows 128w..128w+127), all 4 M-tiles; processed in 4 rounds of 2 N-tiles.
// C/D layout (verified): col = lane&15 (row-dim of W^T), row = 4*(lane>>4)+reg (b).
// A/B k-layout: any consistent permutation cancels between A and B.
// ---------------------------------------------------------------------------
__global__ __launch_bounds__(256) void k_uhat(const float* __restrict__ x,
                                              const float* __restrict__ W,
                                              uint16_t* __restrict__ uhat) {
  const int i = blockIdx.x;
  const int t = threadIdx.x;
  const int w = t >> 6;        // wave 0..3
  const int l = t & 63;
  const int g = l >> 4;        // 16-lane group 0..3
  const int r16 = l & 15;

  // A fragments: lane holds A[row=r16(+16m), k=8g+e]; k>=16 -> 0.
  short8 af[4];
#pragma unroll
  for (int m = 0; m < 4; ++m) {
    short8 f;
#pragma unroll
    for (int e = 0; e < 8; ++e) f[e] = 0;
    if (g < 2) {
      const float* ap = x + (size_t)(16 * m + r16) * (I_ * P_) + (size_t)i * P_ + 8 * g;
      const float4 u0 = *reinterpret_cast<const float4*>(ap);
      const float4 u1 = *reinterpret_cast<const float4*>(ap + 4);
      f[0] = (short)f2bf(u0.x); f[1] = (short)f2bf(u0.y);
      f[2] = (short)f2bf(u0.z); f[3] = (short)f2bf(u0.w);
      f[4] = (short)f2bf(u1.x); f[5] = (short)f2bf(u1.y);
      f[6] = (short)f2bf(u1.z); f[7] = (short)f2bf(u1.w);
    }
    af[m] = f;
  }

  const float* Wi = W + (size_t)i * (ROWS_ * P_);
  uint16_t* out_i = uhat + (size_t)i * ROWS_;

#pragma unroll
  for (int rr = 0; rr < 4; ++rr) {
    // B fragments for 2 N-tiles: lane holds B[k=8g+e, col=16n+r16]; k>=16 -> 0.
    short8 bf[2];
#pragma unroll
    for (int tt = 0; tt < 2; ++tt) {
      const int n = 8 * w + 2 * rr + tt;
      short8 f;
#pragma unroll
      for (int e = 0; e < 8; ++e) f[e] = 0;
      if (g < 2) {
        const float* bp = Wi + (size_t)(16 * n + r16) * P_ + 8 * g;
        const float4 u0 = *reinterpret_cast<const float4*>(bp);
        const float4 u1 = *reinterpret_cast<const float4*>(bp + 4);
        f[0] = (short)f2bf(u0.x); f[1] = (short)f2bf(u0.y);
        f[2] = (short)f2bf(u0.z); f[3] = (short)f2bf(u0.w);
        f[4] = (short)f2bf(u1.x); f[5] = (short)f2bf(u1.y);
        f[6] = (short)f2bf(u1.z); f[7] = (short)f2bf(u1.w);
      }
      bf[tt] = f;
    }

    f32x4 acc[4][2];
#pragma unroll
    for (int m = 0; m < 4; ++m)
#pragma unroll
      for (int tt = 0; tt < 2; ++tt) {
        acc[m][tt][0] = 0.f; acc[m][tt][1] = 0.f;
        acc[m][tt][2] = 0.f; acc[m][tt][3] = 0.f;
      }

#pragma unroll
    for (int m = 0; m < 4; ++m)
#pragma unroll
      for (int tt = 0; tt < 2; ++tt)
        acc[m][tt] = __builtin_amdgcn_mfma_f32_16x16x32_bf16(af[m], bf[tt], acc[m][tt], 0, 0, 0);

    // Epilogue: D[row=b_off, col=rowout]; lane,reg -> b = 16m+4g+r, rowout = 16n+r16.
#pragma unroll
    for (int m = 0; m < 4; ++m)
#pragma unroll
      for (int tt = 0; tt < 2; ++tt) {
        const int n = 8 * w + 2 * rr + tt;
#pragma unroll
        for (int r = 0; r < 4; ++r) {
          const int b = 16 * m + 4 * g + r;
          out_i[(size_t)b * (I_ * ROWS_) + 16 * n + r16] = f2bf(acc[m][tt][r]);
        }
      }
  }
}

// ---------------------------------------------------------------------------
// K_route: one routing pass.
//   UNIFORM: c = 1/32 (pass 0, softmax of zero logits).
//   else:    logit = dot(u, vsum); c = softmax_j(logit)  (no max-subtract:
//            |logit| <= |u||vsum| ~ 6, exp safe in fp32).
// grid = (I/CI, B) x 256. lane&31 = j; 32-wide shfl softmax. Per-lane register
// accumulator over the block's i-range; LDS cross-wave reduce; 512 atomics.
// ---------------------------------------------------------------------------
template <bool UNIFORM>
__global__ __launch_bounds__(256) void k_route(const uint4* __restrict__ uhat,
                                               const float* __restrict__ vsum,
                                               float* __restrict__ s) {
  const int b = blockIdx.y;
  const int i0 = blockIdx.x * CI_;
  const int t = threadIdx.x;
  const int lane = t & 63;
  const int wave = t >> 6;   // 0..3
  const int sub = lane >> 5; // which i of the wave's pair
  const int j = lane & 31;

  float vr[D_];
  if constexpr (!UNIFORM) {
    const float4* vp = reinterpret_cast<const float4*>(vsum + ((size_t)b * J_ + j) * D_);
#pragma unroll
    for (int c4 = 0; c4 < 4; ++c4) {
      const float4 v = vp[c4];
      vr[c4 * 4 + 0] = v.x; vr[c4 * 4 + 1] = v.y;
      vr[c4 * 4 + 2] = v.z; vr[c4 * 4 + 3] = v.w;
    }
  }
  float acc[D_];
#pragma unroll
  for (int d = 0; d < D_; ++d) acc[d] = 0.f;

#pragma unroll 2
  for (int it = 0; it < CI_ / 8; ++it) {
    const int i = i0 + it * 8 + wave * 2 + sub;
    const uint4* up = uhat + (((size_t)b * I_ + i) * J_ + j) * 2;  // 32B row
    const uint4 q0 = up[0], q1 = up[1];
    float u[D_];
    u[0] = bflo(q0.x);  u[1] = bfhi(q0.x);  u[2] = bflo(q0.y);  u[3] = bfhi(q0.y);
    u[4] = bflo(q0.z);  u[5] = bfhi(q0.z);  u[6] = bflo(q0.w);  u[7] = bfhi(q0.w);
    u[8] = bflo(q1.x);  u[9] = bfhi(q1.x);  u[10] = bflo(q1.y); u[11] = bfhi(q1.y);
    u[12] = bflo(q1.z); u[13] = bfhi(q1.z); u[14] = bflo(q1.w); u[15] = bfhi(q1.w);

    if constexpr (UNIFORM) {
#pragma unroll
      for (int d = 0; d < D_; ++d) acc[d] += u[d];
    } else {
      float lg = 0.f;
#pragma unroll
      for (int d = 0; d < D_; ++d) lg = fmaf(u[d], vr[d], lg);
      const float e = __expf(lg);
      float sm = e;
#pragma unroll
      for (int off = 16; off > 0; off >>= 1) sm += __shfl_xor(sm, off, 32);
      const float c = e * __builtin_amdgcn_rcpf(sm);
#pragma unroll
      for (int d = 0; d < D_; ++d) acc[d] = fmaf(c, u[d], acc[d]);
    }
  }
  if constexpr (UNIFORM) {
#pragma unroll
    for (int d = 0; d < D_; ++d) acc[d] *= (1.0f / J_);
  }
  // combine the wave's two i-substreams (lane l <-> l^32, same j)
#pragma unroll
  for (int d = 0; d < D_; ++d) acc[d] += __shfl_xor(acc[d], 32, 64);

  __shared__ float sp[4][J_][D_ + 1];
  if (sub == 0) {
#pragma unroll
    for (int d = 0; d < D_; ++d) sp[wave][j][d] = acc[d];
  }
  __syncthreads();
  for (int k = t; k < J_ * D_; k += 256) {
    const int jj = k >> 4, dd = k & 15;
    atomicAdd(s + (size_t)b * (J_ * D_) + k,
              sp[0][jj][dd] + sp[1][jj][dd] + sp[2][jj][dd] + sp[3][jj][dd]);
  }
}

// ---------------------------------------------------------------------------
// K_squash: v = squash(s); optionally vsum += v; optionally write out.
// ---------------------------------------------------------------------------
__global__ __launch_bounds__(256) void k_squash(const float* __restrict__ s,
                                                float* __restrict__ vsum,
                                                float* __restrict__ out) {
  const int r = blockIdx.x * 256 + threadIdx.x;  // row over B*J
  if (r >= B_ * J_) return;
  const float4* sp = reinterpret_cast<const float4*>(s + (size_t)r * D_);
  float4 a[4] = {sp[0], sp[1], sp[2], sp[3]};
  float n2 = 1e-7f;  // EPS
#pragma unroll
  for (int c = 0; c < 4; ++c)
    n2 += a[c].x * a[c].x + a[c].y * a[c].y + a[c].z * a[c].z + a[c].w * a[c].w;
  const float sc = n2 / ((1.f + n2) * sqrtf(n2));
#pragma unroll
  for (int c = 0; c < 4; ++c) {
    a[c].x *= sc; a[c].y *= sc; a[c].z *= sc; a[c].w *= sc;
  }
  if (vsum) {
    float4* vp = reinterpret_cast<float4*>(vsum + (size_t)r * D_);
#pragma unroll
    for (int c = 0; c < 4; ++c) {
      float4 v = vp[c];
      v.x += a[c].x; v.y += a[c].y; v.z += a[c].z; v.w += a[c].w;
      vp[c] = v;
    }
  }
  if (out) {
    float4* op = reinterpret_cast<float4*>(out + (size_t)r * D_);
#pragma unroll
    for (int c = 0; c < 4; ++c) op[c] = a[c];
  }
}

}  // namespace

extern "C" void kernel_launch(void* const* d_in, const int* in_sizes, int n_in,
                              void* d_out, int out_size, void* d_ws, size_t ws_size,
                              hipStream_t stream) {
  const float* x = (const float*)d_in[0];   // [B, I, P] fp32
  const float* W = (const float*)d_in[1];   // [I, J, D, P] fp32
  float* out = (float*)d_out;               // [B, J, D] fp32

  char* ws = (char*)d_ws;
  uint16_t* uhat = (uint16_t*)ws;                               // 128 MB bf16
  const size_t UHAT_BYTES = (size_t)B_ * I_ * ROWS_ * 2;
  float* s0 = (float*)(ws + UHAT_BYTES);
  float* s1 = s0 + B_ * J_ * D_;
  float* s2 = s1 + B_ * J_ * D_;
  float* vsum = s2 + B_ * J_ * D_;

  hipMemsetAsync(s0, 0, (size_t)4 * B_ * J_ * D_ * sizeof(float), stream);

  k_uhat<<<I_, 256, 0, stream>>>(x, W, uhat);

  const dim3 rg(I_ / CI_, B_);
  k_route<true><<<rg, 256, 0, stream>>>((const uint4*)uhat, vsum, s0);
  k_squash<<<(B_ * J_ + 255) / 256, 256, 0, stream>>>(s0, vsum, nullptr);
  k_route<false><<<rg, 256, 0, stream>>>((const uint4*)uhat, vsum, s1);
  k_squash<<<(B_ * J_ + 255) / 256, 256, 0, stream>>>(s1, vsum, nullptr);
  k_route<false><<<rg, 256, 0, stream>>>((const uint4*)uhat, vsum, s2);
  k_squash<<<(B_ * J_ + 255) / 256, 256, 0, stream>>>(s2, nullptr, out);
}